// Round 13
// baseline (1662.207 us; speedup 1.0000x reference)
//
#include <hip/hip_runtime.h>
#include <hip/hip_bf16.h>
#include <math.h>

#define L_LAYERS 12
#define H_HEADS  12
#define F_DIM    768
#define FH_DIM   64
#define MLPD     3072
#define NT       1025          // 1 + 32*32 tokens
#define NTP      1056          // NT padded to multiple of 32 (zero tail)
#define THREE_F  2304
#define R_REL    3972
#define QK_SCALE 0.125f
#define QB       64            // flash q-tile rows
#define KB       128           // flash kv-tile rows

#define CQKV  (THREE_F * F_DIM)
#define CPROJ (F_DIM * F_DIM)
#define CFC1  (MLPD * F_DIM)
#define CFC2  (F_DIM * MLPD)

typedef short short8_t __attribute__((ext_vector_type(8)));
typedef float f32x4_t  __attribute__((ext_vector_type(4)));
typedef unsigned short u16x4_t __attribute__((ext_vector_type(4)));
typedef __attribute__((address_space(1))) const void* gptr_t;
typedef __attribute__((address_space(3))) void*       lptr_t;

typedef __hip_bfloat16 bf16;

static __device__ inline unsigned short f2bf(float f) {
    __hip_bfloat16 b(f);
    unsigned short u;
    __builtin_memcpy(&u, &b, 2);
    return u;
}

// bijective 8-way XCD chunking over the y-major linearized tile list (m204).
__device__ inline void xcd_remap(int& tx, int& ty) {
    int gx = gridDim.x, gy = gridDim.y;
    int b = blockIdx.y * gx + blockIdx.x;
    int total = gx * gy;
    int q = total >> 3, r = total & 7;
    int xcd = b & 7, i = b >> 3;
    int pos = (xcd < r) ? xcd * (q + 1) + i : r * (q + 1) + (xcd - r) * q + i;
    ty = pos / gx;
    tx = pos - ty * gx;
}

// ------------------------------------------------- one-shot setup (merged) ---
__global__ void setup_k(const float* __restrict__ patch, const float* __restrict__ cls,
                        const int* __restrict__ rp, const float* __restrict__ t,
                        float* __restrict__ x, bf16* __restrict__ vt,
                        unsigned short* __restrict__ rp16, float* __restrict__ tt) {
    const int E0 = NT * F_DIM;
    const int E1 = H_HEADS * FH_DIM * NTP;
    const int E2 = NT * NT;
    const int E3 = L_LAYERS * R_REL * H_HEADS;
    const int total = E0 + E1 + E2 + E3;
    for (int i = blockIdx.x * 256 + threadIdx.x; i < total; i += gridDim.x * 256) {
        if (i < E0) {
            int n = i / F_DIM, f = i - n * F_DIM;
            x[i] = (n == 0) ? cls[f] : patch[(size_t)(n - 1) * F_DIM + f];
        } else if (i < E0 + E1) {
            vt[i - E0] = __hip_bfloat16(0.0f);
        } else if (i < E0 + E1 + E2) {
            int e = i - E0 - E1;
            rp16[e] = (unsigned short)rp[e];
        } else {
            int e = i - E0 - E1 - E2;
            int l = e / (R_REL * H_HEADS), rem = e - l * (R_REL * H_HEADS);
            int rr = rem / H_HEADS, hh = rem - rr * H_HEADS;
            tt[((size_t)l * H_HEADS + hh) * R_REL + rr] = t[e];
        }
    }
}

// -------------------------- ALL weights f32 -> bf16, one dispatch -----------
// single-touch streams: non-temporal loads + stores (skip cache allocation).
__global__ void conv_all_k(const float* __restrict__ qkv_w, const float* __restrict__ proj_w,
                           const float* __restrict__ fc1_w, const float* __restrict__ fc2_w,
                           bf16* __restrict__ wq, bf16* __restrict__ wp,
                           bf16* __restrict__ w1, bf16* __restrict__ w2) {
    const long A1 = (long)L_LAYERS * CQKV;
    const long A2 = A1 + (long)L_LAYERS * CPROJ;
    const long A3 = A2 + (long)L_LAYERS * CFC1;
    const long A4 = A3 + (long)L_LAYERS * CFC2;
    const long total4 = A4 >> 2;
    for (long qd = (long)blockIdx.x * 256 + threadIdx.x; qd < total4;
         qd += (long)gridDim.x * 256) {
        long e = qd << 2;
        const float* s; bf16* d; long off;
        if (e < A1)      { s = qkv_w;  d = wq; off = e; }
        else if (e < A2) { s = proj_w; d = wp; off = e - A1; }
        else if (e < A3) { s = fc1_w;  d = w1; off = e - A2; }
        else             { s = fc2_w;  d = w2; off = e - A3; }
        f32x4_t v = __builtin_nontemporal_load(reinterpret_cast<const f32x4_t*>(s + off));
        u16x4_t o;
        o.x = f2bf(v.x); o.y = f2bf(v.y); o.z = f2bf(v.z); o.w = f2bf(v.w);
        __builtin_nontemporal_store(o, reinterpret_cast<u16x4_t*>(d + off));
    }
}

// -------------------------------------------------------------- layernorm ----
__global__ void layernorm_k(const float* __restrict__ x, const float* __restrict__ w,
                            const float* __restrict__ b, bf16* __restrict__ out) {
    const int row = blockIdx.x;
    const float* xr = x + (size_t)row * F_DIM;
    float v0 = xr[threadIdx.x];
    float v1 = xr[threadIdx.x + 256];
    float v2 = xr[threadIdx.x + 512];
    float s  = v0 + v1 + v2;
    float s2 = v0 * v0 + v1 * v1 + v2 * v2;
    #pragma unroll
    for (int off = 32; off; off >>= 1) {
        s  += __shfl_down(s, off);
        s2 += __shfl_down(s2, off);
    }
    __shared__ float ws_[4], ws2_[4];
    int lane = threadIdx.x & 63, wid = threadIdx.x >> 6;
    if (lane == 0) { ws_[wid] = s; ws2_[wid] = s2; }
    __syncthreads();
    float S  = ws_[0] + ws_[1] + ws_[2] + ws_[3];
    float S2 = ws2_[0] + ws2_[1] + ws2_[2] + ws2_[3];
    float mu  = S * (1.0f / F_DIM);
    float var = S2 * (1.0f / F_DIM) - mu * mu;
    float rs  = rsqrtf(var + 1e-6f);
    bf16* orow = out + (size_t)row * F_DIM;
    orow[threadIdx.x]       = __hip_bfloat16((v0 - mu) * rs * w[threadIdx.x]       + b[threadIdx.x]);
    orow[threadIdx.x + 256] = __hip_bfloat16((v1 - mu) * rs * w[threadIdx.x + 256] + b[threadIdx.x + 256]);
    orow[threadIdx.x + 512] = __hip_bfloat16((v2 - mu) * rs * w[threadIdx.x + 512] + b[threadIdx.x + 512]);
}

// ------------------------------------------------------------- bf16 GEMM -----
// (r9-proven) glds-direct staging, LDS double-buffered, 2-phase prefetch,
// ONE barrier per K-step.
template <int T, int NLOAD>
__device__ inline void stage_glds(const bf16* __restrict__ g0, int ld, int rows_rem,
                                  bf16* lds, int tid) {
    #pragma unroll
    for (int i = 0; i < NLOAD; ++i) {
        int slot = i * T + tid;
        int row = slot >> 3, s = slot & 7;
        int grow = row < rows_rem ? row : (rows_rem - 1);
        const bf16* src = g0 + (size_t)grow * ld + ((s ^ (row & 7)) * 8);
        bf16* dst = lds + (size_t)(i * T + (tid & ~63)) * 8;
        __builtin_amdgcn_global_load_lds((gptr_t)src, (lptr_t)dst, 16, 0, 0);
    }
}

template <int EPI, int BM, int BN, int WM, int WN>
__global__ __launch_bounds__((BM / (WM * 16)) * (BN / (WN * 16)) * 64)
void gemm_k(const bf16* __restrict__ A, const bf16* __restrict__ B,
            int M, int Nc, int K, int lda, int ldb,
            const float* __restrict__ p0, const float* __restrict__ p1,
            float* __restrict__ outF, float* __restrict__ outDup,
            bf16* __restrict__ outB0, bf16* __restrict__ outB1, bf16* __restrict__ outB2) {
    constexpr int NWM = BM / (WM * 16);
    constexpr int NWN = BN / (WN * 16);
    constexpr int T   = NWM * NWN * 64;
    constexpr int ALOADS = BM * 8 / T;
    constexpr int BLOADS = BN * 8 / T;

    __shared__ __align__(16) bf16 As[2][BM * 64];
    __shared__ __align__(16) bf16 Bs[2][BN * 64];

    int tx, ty;
    xcd_remap(tx, ty);
    const int tid  = threadIdx.x;
    const int lane = tid & 63, wid = tid >> 6;
    const int wr = wid / NWN, wc = wid % NWN;
    const int g4 = lane >> 4, l16 = lane & 15;
    const int bm = tx * BM, bn = ty * BN;
    const bf16* Ab = A + (size_t)bm * lda;
    const bf16* Bb = B + (size_t)bn * ldb;
    const int aRows = min(BM, M - bm);
    const int bRows = min(BN, Nc - bn);

    f32x4_t acc[WM][WN] = {};
    const int NK = K >> 6;

    stage_glds<T, ALOADS>(Ab, lda, aRows, As[0], tid);
    stage_glds<T, BLOADS>(Bb, ldb, bRows, Bs[0], tid);
    __syncthreads();

    for (int t = 0; t < NK; ++t) {
        const int c = t & 1;
        if (t + 1 < NK) {
            stage_glds<T, ALOADS>(Ab + (t + 1) * 64, lda, aRows, As[c ^ 1], tid);
            stage_glds<T, BLOADS>(Bb + (t + 1) * 64, ldb, bRows, Bs[c ^ 1], tid);
        }
        const short* AsS = reinterpret_cast<const short*>(As[c]);
        const short* BsS = reinterpret_cast<const short*>(Bs[c]);
        #pragma unroll
        for (int kk = 0; kk < 2; ++kk) {
            short8_t af[WM], bfr[WN];
            #pragma unroll
            for (int mi = 0; mi < WM; ++mi) {
                int ar = wr * WM * 16 + mi * 16 + l16;
                int j = (kk * 4 + g4) ^ (ar & 7);
                af[mi] = *reinterpret_cast<const short8_t*>(AsS + ar * 64 + j * 8);
            }
            #pragma unroll
            for (int ni = 0; ni < WN; ++ni) {
                int br = wc * WN * 16 + ni * 16 + l16;
                int j = (kk * 4 + g4) ^ (br & 7);
                bfr[ni] = *reinterpret_cast<const short8_t*>(BsS + br * 64 + j * 8);
            }
            #pragma unroll
            for (int mi = 0; mi < WM; ++mi)
                #pragma unroll
                for (int ni = 0; ni < WN; ++ni)
                    acc[mi][ni] = __builtin_amdgcn_mfma_f32_16x16x32_bf16(
                        af[mi], bfr[ni], acc[mi][ni], 0, 0, 0);
        }
        __syncthreads();
    }

    #pragma unroll
    for (int mi = 0; mi < WM; ++mi) {
        #pragma unroll
        for (int r = 0; r < 4; ++r) {
            const int row = bm + wr * WM * 16 + mi * 16 + g4 * 4 + r;
            if (row >= M) continue;
            #pragma unroll
            for (int ni = 0; ni < WN; ++ni) {
                const int col = bn + wc * WN * 16 + ni * 16 + l16;
                float v = acc[mi][ni][r];
                if (EPI == 0) {
                    if (col < F_DIM) {
                        int h = col >> 6, d = col & 63;
                        float q = (v + p0[col]) * QK_SCALE;
                        outB0[((size_t)h * NT + row) * 64 + d] = __hip_bfloat16(q);
                    } else if (col < 2 * F_DIM) {
                        int g = col - F_DIM;
                        int h = g >> 6, d = g & 63;
                        outB1[((size_t)h * NT + row) * 64 + d] = __hip_bfloat16(v);
                    } else {
                        int g = col - 2 * F_DIM;
                        int h = g >> 6, d = g & 63;
                        float vv = v + p1[g];
                        outB2[((size_t)h * 64 + d) * NTP + row] = __hip_bfloat16(vv);
                    }
                } else if (EPI == 3) {
                    size_t oi = (size_t)row * Nc + col;
                    v += p0[col];
                    float nv = outF[oi] + p1[col] * v;
                    outF[oi] = nv;
                    if (outDup) outDup[oi] = nv;
                } else if (EPI == 4) {
                    v += p0[col];
                    float g = 0.5f * v * (1.0f + erff(v * 0.70710678118654752f));
                    outB0[(size_t)row * MLPD + col] = __hip_bfloat16(g);
                }
            }
        }
    }
}

// ------------------------------------------------------- fused attention ----
// r9 structure (QB=64, 4 waves, K/V LDS dbuf, 2-phase prefetch, one barrier
// per tile) + T5 setprio around the MFMA clusters (m191: +4-7% on attn).
__global__ __launch_bounds__(256)
void flash_k(const bf16* __restrict__ q_bf, const bf16* __restrict__ k_bf,
             const bf16* __restrict__ v_t, const unsigned short* __restrict__ rp16,
             const float* __restrict__ tableT, bf16* __restrict__ o_bf) {
    __shared__ __align__(16) bf16 Qs[QB * 64];
    __shared__ __align__(16) bf16 Ks[2][KB * 64];
    __shared__ __align__(16) bf16 Vs[2][64 * KB];
    __shared__ __align__(16) bf16 Ps[4][16 * KB];

    int qx, h;
    xcd_remap(qx, h);
    const int tid = threadIdx.x, lane = tid & 63, w = tid >> 6;
    const int qb = qx * QB;
    const bf16* qh = q_bf + (size_t)h * NT * 64;
    const bf16* kh = k_bf + (size_t)h * NT * 64;
    const bf16* vh = v_t  + (size_t)h * 64 * NTP;
    const float* tbl = tableT + (size_t)h * R_REL;
    const int q_local = lane & 15;
    const int g4 = lane >> 4;

    auto stageKV = [&](int buf, int m0) {
        const int kRows = min(KB, NT - m0);
        #pragma unroll
        for (int i = 0; i < 4; ++i) {
            int slot = i * 256 + tid;
            int row = slot >> 3, s = slot & 7;
            int grow = min(row, kRows - 1);
            const bf16* src = kh + (size_t)(m0 + grow) * 64 + (s ^ (row & 7)) * 8;
            bf16* dst = Ks[buf] + (size_t)(i * 256 + (tid & ~63)) * 8;
            __builtin_amdgcn_global_load_lds((gptr_t)src, (lptr_t)dst, 16, 0, 0);
        }
        #pragma unroll
        for (int i = 0; i < 4; ++i) {
            int slot = i * 256 + tid;
            int d = slot >> 4, s = slot & 15;
            int msl = min(m0 / 8 + (s ^ (d & 15)), NTP / 8 - 1);
            const bf16* src = vh + (size_t)d * NTP + msl * 8;
            bf16* dst = Vs[buf] + (size_t)(i * 256 + (tid & ~63)) * 8;
            __builtin_amdgcn_global_load_lds((gptr_t)src, (lptr_t)dst, 16, 0, 0);
        }
    };

    // ---- stage Q + first K/V tile ----
    {
        const int qRows = min(QB, NT - qb);
        #pragma unroll
        for (int i = 0; i < 2; ++i) {
            int slot = i * 256 + tid;
            int row = slot >> 3, s = slot & 7;
            int grow = min(row, qRows - 1);
            const bf16* src = qh + (size_t)(qb + grow) * 64 + (s ^ (row & 7)) * 8;
            bf16* dst = Qs + (size_t)(i * 256 + (tid & ~63)) * 8;
            __builtin_amdgcn_global_load_lds((gptr_t)src, (lptr_t)dst, 16, 0, 0);
        }
    }
    stageKV(0, 0);
    __syncthreads();

    short8_t qf[2];
    {
        const short* QsS = (const short*)Qs;
        #pragma unroll
        for (int kk = 0; kk < 2; ++kk) {
            int row = w * 16 + q_local;
            int slot = (kk * 4 + g4) ^ (row & 7);
            qf[kk] = *(const short8_t*)(QsS + row * 64 + slot * 8);
        }
    }

    float m_run[4], l_run[4];
    f32x4_t acc[4] = {};
    #pragma unroll
    for (int r = 0; r < 4; ++r) { m_run[r] = -1e30f; l_run[r] = 0.0f; }

    const int NTILES = (NT + KB - 1) / KB;   // 9
    for (int t = 0; t < NTILES; ++t) {
        const int m0 = t * KB;
        const int c = t & 1;
        if (t + 1 < NTILES) stageKV(c ^ 1, (t + 1) * KB);  // prefetch next tile

        f32x4_t sfr[8];
        {
            const short* KsS = (const short*)Ks[c];
            __builtin_amdgcn_s_setprio(1);
            #pragma unroll
            for (int f = 0; f < 8; ++f) {
                f32x4_t cacc = {};
                #pragma unroll
                for (int kk = 0; kk < 2; ++kk) {
                    int mrow = f * 16 + q_local;
                    int slot = (kk * 4 + g4) ^ (mrow & 7);
                    short8_t bv = *(const short8_t*)(KsS + mrow * 64 + slot * 8);
                    cacc = __builtin_amdgcn_mfma_f32_16x16x32_bf16(qf[kk], bv, cacc, 0, 0, 0);
                }
                sfr[f] = cacc;
            }
            __builtin_amdgcn_s_setprio(0);
        }

        const int qrow_base = qb + w * 16 + g4 * 4;
        #pragma unroll
        for (int f = 0; f < 8; ++f) {
            int mm = m0 + f * 16 + q_local;
            if (mm < NT) {
                #pragma unroll
                for (int r = 0; r < 4; ++r) {
                    int qc = min(qrow_base + r, NT - 1);
                    int idx = rp16[(size_t)qc * NT + mm];
                    sfr[f][r] += tbl[idx];
                }
            } else {
                #pragma unroll
                for (int r = 0; r < 4; ++r) sfr[f][r] = -1e30f;
            }
        }

        float pmax[4];
        #pragma unroll
        for (int r = 0; r < 4; ++r) {
            float mx = sfr[0][r];
            #pragma unroll
            for (int f = 1; f < 8; ++f) mx = fmaxf(mx, sfr[f][r]);
            pmax[r] = mx;
        }
        #pragma unroll
        for (int off = 1; off < 16; off <<= 1)
            #pragma unroll
            for (int r = 0; r < 4; ++r) pmax[r] = fmaxf(pmax[r], __shfl_xor(pmax[r], off));

        float fac[4];
        #pragma unroll
        for (int r = 0; r < 4; ++r) {
            float mnew = fmaxf(m_run[r], pmax[r]);
            fac[r] = __expf(m_run[r] - mnew);
            m_run[r] = mnew;
        }

        float rsum[4] = {0.f, 0.f, 0.f, 0.f};
        short* PsW = (short*)Ps[w];
        #pragma unroll
        for (int f = 0; f < 8; ++f) {
            int mloc = f * 16 + q_local;
            #pragma unroll
            for (int r = 0; r < 4; ++r) {
                int ql = g4 * 4 + r;
                float p = __expf(sfr[f][r] - m_run[r]);
                rsum[r] += p;
                PsW[ql * 128 + (((mloc >> 3) ^ ql) * 8) + (mloc & 7)] = (short)f2bf(p);
            }
        }
        #pragma unroll
        for (int off = 1; off < 16; off <<= 1)
            #pragma unroll
            for (int r = 0; r < 4; ++r) rsum[r] += __shfl_xor(rsum[r], off);
        #pragma unroll
        for (int r = 0; r < 4; ++r) l_run[r] = l_run[r] * fac[r] + rsum[r];
        #pragma unroll
        for (int df = 0; df < 4; ++df)
            #pragma unroll
            for (int r = 0; r < 4; ++r) acc[df][r] *= fac[r];

        {
            const short* PsR = (const short*)Ps[w];
            const short* VsS = (const short*)Vs[c];
            __builtin_amdgcn_s_setprio(1);
            #pragma unroll
            for (int kk = 0; kk < 4; ++kk) {
                int j = kk * 4 + g4;
                short8_t pa = *(const short8_t*)(PsR + q_local * 128 + (j ^ q_local) * 8);
                #pragma unroll
                for (int df = 0; df < 4; ++df) {
                    int drow = df * 16 + q_local;
                    short8_t vb = *(const short8_t*)(VsS + drow * 128 + (j ^ (drow & 15)) * 8);
                    acc[df] = __builtin_amdgcn_mfma_f32_16x16x32_bf16(pa, vb, acc[df], 0, 0, 0);
                }
            }
            __builtin_amdgcn_s_setprio(0);
        }
        __syncthreads();   // one barrier/tile: drains prefetch, frees buf c
    }

    #pragma unroll
    for (int df = 0; df < 4; ++df) {
        #pragma unroll
        for (int r = 0; r < 4; ++r) {
            int qq = qb + w * 16 + g4 * 4 + r;
            if (qq < NT) {
                float o = acc[df][r] / l_run[r];
                o_bf[(size_t)qq * F_DIM + h * 64 + df * 16 + q_local] = __hip_bfloat16(o);
            }
        }
    }
}

// ------------------------------------------------------------------- host ----
extern "C" void kernel_launch(void* const* d_in, const int* in_sizes, int n_in,
                              void* d_out, int out_size, void* d_ws, size_t ws_size,
                              hipStream_t stream) {
    const float* patch      = (const float*)d_in[0];
    const float* cls        = (const float*)d_in[1];
    const float* ln1_w      = (const float*)d_in[2];
    const float* ln1_b      = (const float*)d_in[3];
    const float* qkv_w      = (const float*)d_in[4];
    const float* q_bias     = (const float*)d_in[5];
    const float* v_bias     = (const float*)d_in[6];
    const float* proj_w     = (const float*)d_in[7];
    const float* proj_b     = (const float*)d_in[8];
    const float* scale_attn = (const float*)d_in[9];
    const float* ln2_w      = (const float*)d_in[10];
    const float* ln2_b      = (const float*)d_in[11];
    const float* fc1_w      = (const float*)d_in[12];
    const float* fc1_b      = (const float*)d_in[13];
    const float* fc2_w      = (const float*)d_in[14];
    const float* fc2_b      = (const float*)d_in[15];
    const float* scale_mlp  = (const float*)d_in[16];
    const float* table      = (const float*)d_in[17];
    const int*   rp_idx     = (const int*)d_in[18];
    float* out = (float*)d_out;

    char* ws = (char*)d_ws;
    size_t off = 0;
    auto alloc = [&](size_t bytes) { char* p = ws + off; off += (bytes + 255) & ~255ULL; return p; };

    float* x      = (float*)alloc((size_t)NT * F_DIM * 4);
    bf16*  h_bf   = (bf16*) alloc((size_t)NT * F_DIM * 2);
    bf16*  q_bf   = (bf16*) alloc((size_t)H_HEADS * NT * 64 * 2);
    bf16*  k_bf   = (bf16*) alloc((size_t)H_HEADS * NT * 64 * 2);
    bf16*  v_t    = (bf16*) alloc((size_t)H_HEADS * 64 * NTP * 2);
    bf16*  o_bf   = (bf16*) alloc((size_t)NT * F_DIM * 2);
    bf16*  m1_bf  = (bf16*) alloc((size_t)NT * MLPD * 2);
    unsigned short* rp16 = (unsigned short*)alloc((size_t)NT * NT * 2);
    float* tableT = (float*)alloc((size_t)L_LAYERS * H_HEADS * R_REL * 4);
    bf16*  wq_all = (bf16*) alloc((size_t)L_LAYERS * CQKV * 2);
    bf16*  wp_all = (bf16*) alloc((size_t)L_LAYERS * CPROJ * 2);
    bf16*  w1_all = (bf16*) alloc((size_t)L_LAYERS * CFC1 * 2);
    bf16*  w2_all = (bf16*) alloc((size_t)L_LAYERS * CFC2 * 2);

    setup_k<<<2048, 256, 0, stream>>>(patch, cls, rp_idx, table, x, v_t, rp16, tableT);
    conv_all_k<<<2048, 256, 0, stream>>>(qkv_w, proj_w, fc1_w, fc2_w,
                                         wq_all, wp_all, w1_all, w2_all);

    int stage = 0;
    for (int l = 0; l < L_LAYERS; ++l) {
        layernorm_k<<<NT, 256, 0, stream>>>(x, ln1_w + l * F_DIM, ln1_b + l * F_DIM, h_bf);

        gemm_k<0, 64, 128, 2, 2><<<dim3(17, 18), 512, 0, stream>>>(
            h_bf, wq_all + (size_t)l * CQKV, NT, THREE_F, F_DIM, F_DIM, F_DIM,
            q_bias + (size_t)l * F_DIM, v_bias + (size_t)l * F_DIM,
            nullptr, nullptr, q_bf, k_bf, v_t);

        flash_k<<<dim3((NT + QB - 1) / QB, H_HEADS), 256, 0, stream>>>(
            q_bf, k_bf, v_t, rp16,
            tableT + (size_t)l * H_HEADS * R_REL, o_bf);

        gemm_k<3, 32, 64, 1, 2><<<dim3(33, 12), 256, 0, stream>>>(
            o_bf, wp_all + (size_t)l * CPROJ, NT, F_DIM, F_DIM, F_DIM, F_DIM,
            proj_b + (size_t)l * F_DIM, scale_attn + (size_t)l * F_DIM,
            x, nullptr, nullptr, nullptr, nullptr);

        layernorm_k<<<NT, 256, 0, stream>>>(x, ln2_w + l * F_DIM, ln2_b + l * F_DIM, h_bf);

        gemm_k<4, 64, 128, 2, 2><<<dim3(17, 24), 512, 0, stream>>>(
            h_bf, w1_all + (size_t)l * CFC1, NT, MLPD, F_DIM, F_DIM, F_DIM,
            fc1_b + (size_t)l * MLPD, nullptr,
            nullptr, nullptr, m1_bf, nullptr, nullptr);

        const bool isStage = (l == 2 || l == 5 || l == 8 || l == 11);
        float* outDup = isStage ? (out + (size_t)stage * NT * F_DIM) : nullptr;
        gemm_k<3, 32, 64, 1, 2><<<dim3(33, 12), 256, 0, stream>>>(
            m1_bf, w2_all + (size_t)l * CFC2, NT, F_DIM, MLPD, MLPD, MLPD,
            fc2_b + (size_t)l * F_DIM, scale_mlp + (size_t)l * F_DIM,
            x, outDup, nullptr, nullptr, nullptr);
        if (isStage) ++stage;
    }
}

// Round 14
// 1650.668 us; speedup vs baseline: 1.0070x; 1.0070x over previous
//
#include <hip/hip_runtime.h>
#include <hip/hip_bf16.h>
#include <math.h>

#define L_LAYERS 12
#define H_HEADS  12
#define F_DIM    768
#define FH_DIM   64
#define MLPD     3072
#define NT       1025          // 1 + 32*32 tokens
#define NTP      1056          // NT padded to multiple of 32 (zero tail)
#define THREE_F  2304
#define R_REL    3972
#define QK_SCALE 0.125f
#define QB       64            // flash q-tile rows
#define KB       128           // flash kv-tile rows

#define CQKV  (THREE_F * F_DIM)
#define CPROJ (F_DIM * F_DIM)
#define CFC1  (MLPD * F_DIM)
#define CFC2  (F_DIM * MLPD)

typedef short short8_t __attribute__((ext_vector_type(8)));
typedef float f32x4_t  __attribute__((ext_vector_type(4)));
typedef unsigned short u16x4_t __attribute__((ext_vector_type(4)));
typedef __attribute__((address_space(1))) const void* gptr_t;
typedef __attribute__((address_space(3))) void*       lptr_t;

typedef __hip_bfloat16 bf16;

static __device__ inline unsigned short f2bf(float f) {
    __hip_bfloat16 b(f);
    unsigned short u;
    __builtin_memcpy(&u, &b, 2);
    return u;
}

// bijective 8-way XCD chunking over the y-major linearized tile list (m204).
__device__ inline void xcd_remap(int& tx, int& ty) {
    int gx = gridDim.x, gy = gridDim.y;
    int b = blockIdx.y * gx + blockIdx.x;
    int total = gx * gy;
    int q = total >> 3, r = total & 7;
    int xcd = b & 7, i = b >> 3;
    int pos = (xcd < r) ? xcd * (q + 1) + i : r * (q + 1) + (xcd - r) * q + i;
    ty = pos / gx;
    tx = pos - ty * gx;
}

// ------------------------------------------------- one-shot setup (merged) ---
__global__ void setup_k(const float* __restrict__ patch, const float* __restrict__ cls,
                        const int* __restrict__ rp, const float* __restrict__ t,
                        float* __restrict__ x, bf16* __restrict__ vt,
                        unsigned short* __restrict__ rp16, float* __restrict__ tt) {
    const int E0 = NT * F_DIM;
    const int E1 = H_HEADS * FH_DIM * NTP;
    const int E2 = NT * NT;
    const int E3 = L_LAYERS * R_REL * H_HEADS;
    const int total = E0 + E1 + E2 + E3;
    for (int i = blockIdx.x * 256 + threadIdx.x; i < total; i += gridDim.x * 256) {
        if (i < E0) {
            int n = i / F_DIM, f = i - n * F_DIM;
            x[i] = (n == 0) ? cls[f] : patch[(size_t)(n - 1) * F_DIM + f];
        } else if (i < E0 + E1) {
            vt[i - E0] = __hip_bfloat16(0.0f);
        } else if (i < E0 + E1 + E2) {
            int e = i - E0 - E1;
            rp16[e] = (unsigned short)rp[e];
        } else {
            int e = i - E0 - E1 - E2;
            int l = e / (R_REL * H_HEADS), rem = e - l * (R_REL * H_HEADS);
            int rr = rem / H_HEADS, hh = rem - rr * H_HEADS;
            tt[((size_t)l * H_HEADS + hh) * R_REL + rr] = t[e];
        }
    }
}

// -------------------------- ALL weights f32 -> bf16, one dispatch -----------
// single-touch streams: non-temporal loads + stores (skip cache allocation).
__global__ void conv_all_k(const float* __restrict__ qkv_w, const float* __restrict__ proj_w,
                           const float* __restrict__ fc1_w, const float* __restrict__ fc2_w,
                           bf16* __restrict__ wq, bf16* __restrict__ wp,
                           bf16* __restrict__ w1, bf16* __restrict__ w2) {
    const long A1 = (long)L_LAYERS * CQKV;
    const long A2 = A1 + (long)L_LAYERS * CPROJ;
    const long A3 = A2 + (long)L_LAYERS * CFC1;
    const long A4 = A3 + (long)L_LAYERS * CFC2;
    const long total4 = A4 >> 2;
    for (long qd = (long)blockIdx.x * 256 + threadIdx.x; qd < total4;
         qd += (long)gridDim.x * 256) {
        long e = qd << 2;
        const float* s; bf16* d; long off;
        if (e < A1)      { s = qkv_w;  d = wq; off = e; }
        else if (e < A2) { s = proj_w; d = wp; off = e - A1; }
        else if (e < A3) { s = fc1_w;  d = w1; off = e - A2; }
        else             { s = fc2_w;  d = w2; off = e - A3; }
        f32x4_t v = __builtin_nontemporal_load(reinterpret_cast<const f32x4_t*>(s + off));
        u16x4_t o;
        o.x = f2bf(v.x); o.y = f2bf(v.y); o.z = f2bf(v.z); o.w = f2bf(v.w);
        __builtin_nontemporal_store(o, reinterpret_cast<u16x4_t*>(d + off));
    }
}

// -------------------------------------------------------------- layernorm ----
__global__ void layernorm_k(const float* __restrict__ x, const float* __restrict__ w,
                            const float* __restrict__ b, bf16* __restrict__ out) {
    const int row = blockIdx.x;
    const float* xr = x + (size_t)row * F_DIM;
    float v0 = xr[threadIdx.x];
    float v1 = xr[threadIdx.x + 256];
    float v2 = xr[threadIdx.x + 512];
    float s  = v0 + v1 + v2;
    float s2 = v0 * v0 + v1 * v1 + v2 * v2;
    #pragma unroll
    for (int off = 32; off; off >>= 1) {
        s  += __shfl_down(s, off);
        s2 += __shfl_down(s2, off);
    }
    __shared__ float ws_[4], ws2_[4];
    int lane = threadIdx.x & 63, wid = threadIdx.x >> 6;
    if (lane == 0) { ws_[wid] = s; ws2_[wid] = s2; }
    __syncthreads();
    float S  = ws_[0] + ws_[1] + ws_[2] + ws_[3];
    float S2 = ws2_[0] + ws2_[1] + ws2_[2] + ws2_[3];
    float mu  = S * (1.0f / F_DIM);
    float var = S2 * (1.0f / F_DIM) - mu * mu;
    float rs  = rsqrtf(var + 1e-6f);
    bf16* orow = out + (size_t)row * F_DIM;
    orow[threadIdx.x]       = __hip_bfloat16((v0 - mu) * rs * w[threadIdx.x]       + b[threadIdx.x]);
    orow[threadIdx.x + 256] = __hip_bfloat16((v1 - mu) * rs * w[threadIdx.x + 256] + b[threadIdx.x + 256]);
    orow[threadIdx.x + 512] = __hip_bfloat16((v2 - mu) * rs * w[threadIdx.x + 512] + b[threadIdx.x + 512]);
}

// ------------------------------------------------------------- bf16 GEMM -----
// (r9-proven) glds-direct staging, LDS double-buffered, 2-phase prefetch,
// ONE barrier per K-step.
template <int T, int NLOAD>
__device__ inline void stage_glds(const bf16* __restrict__ g0, int ld, int rows_rem,
                                  bf16* lds, int tid) {
    #pragma unroll
    for (int i = 0; i < NLOAD; ++i) {
        int slot = i * T + tid;
        int row = slot >> 3, s = slot & 7;
        int grow = row < rows_rem ? row : (rows_rem - 1);
        const bf16* src = g0 + (size_t)grow * ld + ((s ^ (row & 7)) * 8);
        bf16* dst = lds + (size_t)(i * T + (tid & ~63)) * 8;
        __builtin_amdgcn_global_load_lds((gptr_t)src, (lptr_t)dst, 16, 0, 0);
    }
}

template <int EPI, int BM, int BN, int WM, int WN>
__global__ __launch_bounds__((BM / (WM * 16)) * (BN / (WN * 16)) * 64)
void gemm_k(const bf16* __restrict__ A, const bf16* __restrict__ B,
            int M, int Nc, int K, int lda, int ldb,
            const float* __restrict__ p0, const float* __restrict__ p1,
            float* __restrict__ outF, float* __restrict__ outDup,
            bf16* __restrict__ outB0, bf16* __restrict__ outB1, bf16* __restrict__ outB2) {
    constexpr int NWM = BM / (WM * 16);
    constexpr int NWN = BN / (WN * 16);
    constexpr int T   = NWM * NWN * 64;
    constexpr int ALOADS = BM * 8 / T;
    constexpr int BLOADS = BN * 8 / T;

    __shared__ __align__(16) bf16 As[2][BM * 64];
    __shared__ __align__(16) bf16 Bs[2][BN * 64];

    int tx, ty;
    xcd_remap(tx, ty);
    const int tid  = threadIdx.x;
    const int lane = tid & 63, wid = tid >> 6;
    const int wr = wid / NWN, wc = wid % NWN;
    const int g4 = lane >> 4, l16 = lane & 15;
    const int bm = tx * BM, bn = ty * BN;
    const bf16* Ab = A + (size_t)bm * lda;
    const bf16* Bb = B + (size_t)bn * ldb;
    const int aRows = min(BM, M - bm);
    const int bRows = min(BN, Nc - bn);

    f32x4_t acc[WM][WN] = {};
    const int NK = K >> 6;

    stage_glds<T, ALOADS>(Ab, lda, aRows, As[0], tid);
    stage_glds<T, BLOADS>(Bb, ldb, bRows, Bs[0], tid);
    __syncthreads();

    for (int t = 0; t < NK; ++t) {
        const int c = t & 1;
        if (t + 1 < NK) {
            stage_glds<T, ALOADS>(Ab + (t + 1) * 64, lda, aRows, As[c ^ 1], tid);
            stage_glds<T, BLOADS>(Bb + (t + 1) * 64, ldb, bRows, Bs[c ^ 1], tid);
        }
        const short* AsS = reinterpret_cast<const short*>(As[c]);
        const short* BsS = reinterpret_cast<const short*>(Bs[c]);
        #pragma unroll
        for (int kk = 0; kk < 2; ++kk) {
            short8_t af[WM], bfr[WN];
            #pragma unroll
            for (int mi = 0; mi < WM; ++mi) {
                int ar = wr * WM * 16 + mi * 16 + l16;
                int j = (kk * 4 + g4) ^ (ar & 7);
                af[mi] = *reinterpret_cast<const short8_t*>(AsS + ar * 64 + j * 8);
            }
            #pragma unroll
            for (int ni = 0; ni < WN; ++ni) {
                int br = wc * WN * 16 + ni * 16 + l16;
                int j = (kk * 4 + g4) ^ (br & 7);
                bfr[ni] = *reinterpret_cast<const short8_t*>(BsS + br * 64 + j * 8);
            }
            #pragma unroll
            for (int mi = 0; mi < WM; ++mi)
                #pragma unroll
                for (int ni = 0; ni < WN; ++ni)
                    acc[mi][ni] = __builtin_amdgcn_mfma_f32_16x16x32_bf16(
                        af[mi], bfr[ni], acc[mi][ni], 0, 0, 0);
        }
        __syncthreads();
    }

    #pragma unroll
    for (int mi = 0; mi < WM; ++mi) {
        #pragma unroll
        for (int r = 0; r < 4; ++r) {
            const int row = bm + wr * WM * 16 + mi * 16 + g4 * 4 + r;
            if (row >= M) continue;
            #pragma unroll
            for (int ni = 0; ni < WN; ++ni) {
                const int col = bn + wc * WN * 16 + ni * 16 + l16;
                float v = acc[mi][ni][r];
                if (EPI == 0) {
                    if (col < F_DIM) {
                        int h = col >> 6, d = col & 63;
                        float q = (v + p0[col]) * QK_SCALE;
                        outB0[((size_t)h * NT + row) * 64 + d] = __hip_bfloat16(q);
                    } else if (col < 2 * F_DIM) {
                        int g = col - F_DIM;
                        int h = g >> 6, d = g & 63;
                        outB1[((size_t)h * NT + row) * 64 + d] = __hip_bfloat16(v);
                    } else {
                        int g = col - 2 * F_DIM;
                        int h = g >> 6, d = g & 63;
                        float vv = v + p1[g];
                        outB2[((size_t)h * 64 + d) * NTP + row] = __hip_bfloat16(vv);
                    }
                } else if (EPI == 3) {
                    size_t oi = (size_t)row * Nc + col;
                    v += p0[col];
                    float nv = outF[oi] + p1[col] * v;
                    outF[oi] = nv;
                    if (outDup) outDup[oi] = nv;
                } else if (EPI == 4) {
                    v += p0[col];
                    float g = 0.5f * v * (1.0f + erff(v * 0.70710678118654752f));
                    outB0[(size_t)row * MLPD + col] = __hip_bfloat16(g);
                }
            }
        }
    }
}

// ------------------------------------------------------- fused attention ----
// r9 structure (QB=64, 4 waves, K/V LDS dbuf, 2-phase prefetch, one barrier
// per tile).  NO setprio: barrier-lockstep waves (m190-class null/negative).
__global__ __launch_bounds__(256)
void flash_k(const bf16* __restrict__ q_bf, const bf16* __restrict__ k_bf,
             const bf16* __restrict__ v_t, const unsigned short* __restrict__ rp16,
             const float* __restrict__ tableT, bf16* __restrict__ o_bf) {
    __shared__ __align__(16) bf16 Qs[QB * 64];
    __shared__ __align__(16) bf16 Ks[2][KB * 64];
    __shared__ __align__(16) bf16 Vs[2][64 * KB];
    __shared__ __align__(16) bf16 Ps[4][16 * KB];

    int qx, h;
    xcd_remap(qx, h);
    const int tid = threadIdx.x, lane = tid & 63, w = tid >> 6;
    const int qb = qx * QB;
    const bf16* qh = q_bf + (size_t)h * NT * 64;
    const bf16* kh = k_bf + (size_t)h * NT * 64;
    const bf16* vh = v_t  + (size_t)h * 64 * NTP;
    const float* tbl = tableT + (size_t)h * R_REL;
    const int q_local = lane & 15;
    const int g4 = lane >> 4;

    auto stageKV = [&](int buf, int m0) {
        const int kRows = min(KB, NT - m0);
        #pragma unroll
        for (int i = 0; i < 4; ++i) {
            int slot = i * 256 + tid;
            int row = slot >> 3, s = slot & 7;
            int grow = min(row, kRows - 1);
            const bf16* src = kh + (size_t)(m0 + grow) * 64 + (s ^ (row & 7)) * 8;
            bf16* dst = Ks[buf] + (size_t)(i * 256 + (tid & ~63)) * 8;
            __builtin_amdgcn_global_load_lds((gptr_t)src, (lptr_t)dst, 16, 0, 0);
        }
        #pragma unroll
        for (int i = 0; i < 4; ++i) {
            int slot = i * 256 + tid;
            int d = slot >> 4, s = slot & 15;
            int msl = min(m0 / 8 + (s ^ (d & 15)), NTP / 8 - 1);
            const bf16* src = vh + (size_t)d * NTP + msl * 8;
            bf16* dst = Vs[buf] + (size_t)(i * 256 + (tid & ~63)) * 8;
            __builtin_amdgcn_global_load_lds((gptr_t)src, (lptr_t)dst, 16, 0, 0);
        }
    };

    // ---- stage Q + first K/V tile ----
    {
        const int qRows = min(QB, NT - qb);
        #pragma unroll
        for (int i = 0; i < 2; ++i) {
            int slot = i * 256 + tid;
            int row = slot >> 3, s = slot & 7;
            int grow = min(row, qRows - 1);
            const bf16* src = qh + (size_t)(qb + grow) * 64 + (s ^ (row & 7)) * 8;
            bf16* dst = Qs + (size_t)(i * 256 + (tid & ~63)) * 8;
            __builtin_amdgcn_global_load_lds((gptr_t)src, (lptr_t)dst, 16, 0, 0);
        }
    }
    stageKV(0, 0);
    __syncthreads();

    short8_t qf[2];
    {
        const short* QsS = (const short*)Qs;
        #pragma unroll
        for (int kk = 0; kk < 2; ++kk) {
            int row = w * 16 + q_local;
            int slot = (kk * 4 + g4) ^ (row & 7);
            qf[kk] = *(const short8_t*)(QsS + row * 64 + slot * 8);
        }
    }

    float m_run[4], l_run[4];
    f32x4_t acc[4] = {};
    #pragma unroll
    for (int r = 0; r < 4; ++r) { m_run[r] = -1e30f; l_run[r] = 0.0f; }

    const int NTILES = (NT + KB - 1) / KB;   // 9
    for (int t = 0; t < NTILES; ++t) {
        const int m0 = t * KB;
        const int c = t & 1;
        if (t + 1 < NTILES) stageKV(c ^ 1, (t + 1) * KB);  // prefetch next tile

        f32x4_t sfr[8];
        {
            const short* KsS = (const short*)Ks[c];
            #pragma unroll
            for (int f = 0; f < 8; ++f) {
                f32x4_t cacc = {};
                #pragma unroll
                for (int kk = 0; kk < 2; ++kk) {
                    int mrow = f * 16 + q_local;
                    int slot = (kk * 4 + g4) ^ (mrow & 7);
                    short8_t bv = *(const short8_t*)(KsS + mrow * 64 + slot * 8);
                    cacc = __builtin_amdgcn_mfma_f32_16x16x32_bf16(qf[kk], bv, cacc, 0, 0, 0);
                }
                sfr[f] = cacc;
            }
        }

        const int qrow_base = qb + w * 16 + g4 * 4;
        #pragma unroll
        for (int f = 0; f < 8; ++f) {
            int mm = m0 + f * 16 + q_local;
            if (mm < NT) {
                #pragma unroll
                for (int r = 0; r < 4; ++r) {
                    int qc = min(qrow_base + r, NT - 1);
                    int idx = rp16[(size_t)qc * NT + mm];
                    sfr[f][r] += tbl[idx];
                }
            } else {
                #pragma unroll
                for (int r = 0; r < 4; ++r) sfr[f][r] = -1e30f;
            }
        }

        float pmax[4];
        #pragma unroll
        for (int r = 0; r < 4; ++r) {
            float mx = sfr[0][r];
            #pragma unroll
            for (int f = 1; f < 8; ++f) mx = fmaxf(mx, sfr[f][r]);
            pmax[r] = mx;
        }
        #pragma unroll
        for (int off = 1; off < 16; off <<= 1)
            #pragma unroll
            for (int r = 0; r < 4; ++r) pmax[r] = fmaxf(pmax[r], __shfl_xor(pmax[r], off));

        float fac[4];
        #pragma unroll
        for (int r = 0; r < 4; ++r) {
            float mnew = fmaxf(m_run[r], pmax[r]);
            fac[r] = __expf(m_run[r] - mnew);
            m_run[r] = mnew;
        }

        float rsum[4] = {0.f, 0.f, 0.f, 0.f};
        short* PsW = (short*)Ps[w];
        #pragma unroll
        for (int f = 0; f < 8; ++f) {
            int mloc = f * 16 + q_local;
            #pragma unroll
            for (int r = 0; r < 4; ++r) {
                int ql = g4 * 4 + r;
                float p = __expf(sfr[f][r] - m_run[r]);
                rsum[r] += p;
                PsW[ql * 128 + (((mloc >> 3) ^ ql) * 8) + (mloc & 7)] = (short)f2bf(p);
            }
        }
        #pragma unroll
        for (int off = 1; off < 16; off <<= 1)
            #pragma unroll
            for (int r = 0; r < 4; ++r) rsum[r] += __shfl_xor(rsum[r], off);
        #pragma unroll
        for (int r = 0; r < 4; ++r) l_run[r] = l_run[r] * fac[r] + rsum[r];
        #pragma unroll
        for (int df = 0; df < 4; ++df)
            #pragma unroll
            for (int r = 0; r < 4; ++r) acc[df][r] *= fac[r];

        {
            const short* PsR = (const short*)Ps[w];
            const short* VsS = (const short*)Vs[c];
            #pragma unroll
            for (int kk = 0; kk < 4; ++kk) {
                int j = kk * 4 + g4;
                short8_t pa = *(const short8_t*)(PsR + q_local * 128 + (j ^ q_local) * 8);
                #pragma unroll
                for (int df = 0; df < 4; ++df) {
                    int drow = df * 16 + q_local;
                    short8_t vb = *(const short8_t*)(VsS + drow * 128 + (j ^ (drow & 15)) * 8);
                    acc[df] = __builtin_amdgcn_mfma_f32_16x16x32_bf16(pa, vb, acc[df], 0, 0, 0);
                }
            }
        }
        __syncthreads();   // one barrier/tile: drains prefetch, frees buf c
    }

    #pragma unroll
    for (int df = 0; df < 4; ++df) {
        #pragma unroll
        for (int r = 0; r < 4; ++r) {
            int qq = qb + w * 16 + g4 * 4 + r;
            if (qq < NT) {
                float o = acc[df][r] / l_run[r];
                o_bf[(size_t)qq * F_DIM + h * 64 + df * 16 + q_local] = __hip_bfloat16(o);
            }
        }
    }
}

// ------------------------------------------------------------------- host ----
extern "C" void kernel_launch(void* const* d_in, const int* in_sizes, int n_in,
                              void* d_out, int out_size, void* d_ws, size_t ws_size,
                              hipStream_t stream) {
    const float* patch      = (const float*)d_in[0];
    const float* cls        = (const float*)d_in[1];
    const float* ln1_w      = (const float*)d_in[2];
    const float* ln1_b      = (const float*)d_in[3];
    const float* qkv_w      = (const float*)d_in[4];
    const float* q_bias     = (const float*)d_in[5];
    const float* v_bias     = (const float*)d_in[6];
    const float* proj_w     = (const float*)d_in[7];
    const float* proj_b     = (const float*)d_in[8];
    const float* scale_attn = (const float*)d_in[9];
    const float* ln2_w      = (const float*)d_in[10];
    const float* ln2_b      = (const float*)d_in[11];
    const float* fc1_w      = (const float*)d_in[12];
    const float* fc1_b      = (const float*)d_in[13];
    const float* fc2_w      = (const float*)d_in[14];
    const float* fc2_b      = (const float*)d_in[15];
    const float* scale_mlp  = (const float*)d_in[16];
    const float* table      = (const float*)d_in[17];
    const int*   rp_idx     = (const int*)d_in[18];
    float* out = (float*)d_out;

    char* ws = (char*)d_ws;
    size_t off = 0;
    auto alloc = [&](size_t bytes) { char* p = ws + off; off += (bytes + 255) & ~255ULL; return p; };

    float* x      = (float*)alloc((size_t)NT * F_DIM * 4);
    bf16*  h_bf   = (bf16*) alloc((size_t)NT * F_DIM * 2);
    bf16*  q_bf   = (bf16*) alloc((size_t)H_HEADS * NT * 64 * 2);
    bf16*  k_bf   = (bf16*) alloc((size_t)H_HEADS * NT * 64 * 2);
    bf16*  v_t    = (bf16*) alloc((size_t)H_HEADS * 64 * NTP * 2);
    bf16*  o_bf   = (bf16*) alloc((size_t)NT * F_DIM * 2);
    bf16*  m1_bf  = (bf16*) alloc((size_t)NT * MLPD * 2);
    unsigned short* rp16 = (unsigned short*)alloc((size_t)NT * NT * 2);
    float* tableT = (float*)alloc((size_t)L_LAYERS * H_HEADS * R_REL * 4);
    bf16*  wq_all = (bf16*) alloc((size_t)L_LAYERS * CQKV * 2);
    bf16*  wp_all = (bf16*) alloc((size_t)L_LAYERS * CPROJ * 2);
    bf16*  w1_all = (bf16*) alloc((size_t)L_LAYERS * CFC1 * 2);
    bf16*  w2_all = (bf16*) alloc((size_t)L_LAYERS * CFC2 * 2);

    setup_k<<<2048, 256, 0, stream>>>(patch, cls, rp_idx, table, x, v_t, rp16, tableT);
    conv_all_k<<<2048, 256, 0, stream>>>(qkv_w, proj_w, fc1_w, fc2_w,
                                         wq_all, wp_all, w1_all, w2_all);

    int stage = 0;
    for (int l = 0; l < L_LAYERS; ++l) {
        layernorm_k<<<NT, 256, 0, stream>>>(x, ln1_w + l * F_DIM, ln1_b + l * F_DIM, h_bf);

        gemm_k<0, 64, 128, 2, 2><<<dim3(17, 18), 512, 0, stream>>>(
            h_bf, wq_all + (size_t)l * CQKV, NT, THREE_F, F_DIM, F_DIM, F_DIM,
            q_bias + (size_t)l * F_DIM, v_bias + (size_t)l * F_DIM,
            nullptr, nullptr, q_bf, k_bf, v_t);

        flash_k<<<dim3((NT + QB - 1) / QB, H_HEADS), 256, 0, stream>>>(
            q_bf, k_bf, v_t, rp16,
            tableT + (size_t)l * H_HEADS * R_REL, o_bf);

        gemm_k<3, 32, 64, 1, 2><<<dim3(33, 12), 256, 0, stream>>>(
            o_bf, wp_all + (size_t)l * CPROJ, NT, F_DIM, F_DIM, F_DIM, F_DIM,
            proj_b + (size_t)l * F_DIM, scale_attn + (size_t)l * F_DIM,
            x, nullptr, nullptr, nullptr, nullptr);

        layernorm_k<<<NT, 256, 0, stream>>>(x, ln2_w + l * F_DIM, ln2_b + l * F_DIM, h_bf);

        gemm_k<4, 64, 128, 2, 2><<<dim3(17, 24), 512, 0, stream>>>(
            h_bf, w1_all + (size_t)l * CFC1, NT, MLPD, F_DIM, F_DIM, F_DIM,
            fc1_b + (size_t)l * MLPD, nullptr,
            nullptr, nullptr, m1_bf, nullptr, nullptr);

        const bool isStage = (l == 2 || l == 5 || l == 8 || l == 11);
        float* outDup = isStage ? (out + (size_t)stage * NT * F_DIM) : nullptr;
        gemm_k<3, 32, 64, 1, 2><<<dim3(33, 12), 256, 0, stream>>>(
            m1_bf, w2_all + (size_t)l * CFC2, NT, F_DIM, MLPD, MLPD, MLPD,
            fc2_b + (size_t)l * F_DIM, scale_mlp + (size_t)l * F_DIM,
            x, outDup, nullptr, nullptr, nullptr);
        if (isStage) ++stage;
    }
}

// Round 15
// 1411.398 us; speedup vs baseline: 1.1777x; 1.1695x over previous
//
#include <hip/hip_runtime.h>
#include <hip/hip_bf16.h>
#include <math.h>

#define L_LAYERS 12
#define H_HEADS  12
#define F_DIM    768
#define FH_DIM   64
#define MLPD     3072
#define NT       1025          // 1 + 32*32 tokens
#define NTP      1056          // NT padded to multiple of 32 (zero tail)
#define THREE_F  2304
#define R_REL    3972
#define QK_SCALE 0.125f
#define QB       64            // flash q-tile rows
#define KB       128           // flash kv-tile rows

#define CQKV  (THREE_F * F_DIM)
#define CPROJ (F_DIM * F_DIM)
#define CFC1  (MLPD * F_DIM)
#define CFC2  (F_DIM * MLPD)

typedef short short8_t __attribute__((ext_vector_type(8)));
typedef float f32x4_t  __attribute__((ext_vector_type(4)));
typedef unsigned short u16x4_t __attribute__((ext_vector_type(4)));
typedef __attribute__((address_space(1))) const void* gptr_t;
typedef __attribute__((address_space(3))) void*       lptr_t;

typedef __hip_bfloat16 bf16;

static __device__ inline unsigned short f2bf(float f) {
    __hip_bfloat16 b(f);
    unsigned short u;
    __builtin_memcpy(&u, &b, 2);
    return u;
}

// bijective 8-way XCD chunking over the y-major linearized tile list (m204).
__device__ inline void xcd_remap(int& tx, int& ty) {
    int gx = gridDim.x, gy = gridDim.y;
    int b = blockIdx.y * gx + blockIdx.x;
    int total = gx * gy;
    int q = total >> 3, r = total & 7;
    int xcd = b & 7, i = b >> 3;
    int pos = (xcd < r) ? xcd * (q + 1) + i : r * (q + 1) + (xcd - r) * q + i;
    ty = pos / gx;
    tx = pos - ty * gx;
}

// ------------------------------------------------- one-shot setup (merged) ---
__global__ void setup_k(const float* __restrict__ patch, const float* __restrict__ cls,
                        const int* __restrict__ rp, const float* __restrict__ t,
                        float* __restrict__ x, bf16* __restrict__ vt,
                        unsigned short* __restrict__ rp16, float* __restrict__ tt) {
    const int E0 = NT * F_DIM;
    const int E1 = H_HEADS * FH_DIM * NTP;
    const int E2 = NT * NT;
    const int E3 = L_LAYERS * R_REL * H_HEADS;
    const int total = E0 + E1 + E2 + E3;
    for (int i = blockIdx.x * 256 + threadIdx.x; i < total; i += gridDim.x * 256) {
        if (i < E0) {
            int n = i / F_DIM, f = i - n * F_DIM;
            x[i] = (n == 0) ? cls[f] : patch[(size_t)(n - 1) * F_DIM + f];
        } else if (i < E0 + E1) {
            vt[i - E0] = __hip_bfloat16(0.0f);
        } else if (i < E0 + E1 + E2) {
            int e = i - E0 - E1;
            rp16[e] = (unsigned short)rp[e];
        } else {
            int e = i - E0 - E1 - E2;
            int l = e / (R_REL * H_HEADS), rem = e - l * (R_REL * H_HEADS);
            int rr = rem / H_HEADS, hh = rem - rr * H_HEADS;
            tt[((size_t)l * H_HEADS + hh) * R_REL + rr] = t[e];
        }
    }
}

// -------------------------- ALL weights f32 -> bf16, one dispatch -----------
// f32 source is single-touch -> non-temporal LOAD.  bf16 dest is RE-READ by
// every GEMM -> regular cached store (r13's nt-store bypassed L3 and slowed
// all downstream weight reads).
__global__ void conv_all_k(const float* __restrict__ qkv_w, const float* __restrict__ proj_w,
                           const float* __restrict__ fc1_w, const float* __restrict__ fc2_w,
                           bf16* __restrict__ wq, bf16* __restrict__ wp,
                           bf16* __restrict__ w1, bf16* __restrict__ w2) {
    const long A1 = (long)L_LAYERS * CQKV;
    const long A2 = A1 + (long)L_LAYERS * CPROJ;
    const long A3 = A2 + (long)L_LAYERS * CFC1;
    const long A4 = A3 + (long)L_LAYERS * CFC2;
    const long total4 = A4 >> 2;
    for (long qd = (long)blockIdx.x * 256 + threadIdx.x; qd < total4;
         qd += (long)gridDim.x * 256) {
        long e = qd << 2;
        const float* s; bf16* d; long off;
        if (e < A1)      { s = qkv_w;  d = wq; off = e; }
        else if (e < A2) { s = proj_w; d = wp; off = e - A1; }
        else if (e < A3) { s = fc1_w;  d = w1; off = e - A2; }
        else             { s = fc2_w;  d = w2; off = e - A3; }
        f32x4_t v = __builtin_nontemporal_load(reinterpret_cast<const f32x4_t*>(s + off));
        u16x4_t o;
        o.x = f2bf(v.x); o.y = f2bf(v.y); o.z = f2bf(v.z); o.w = f2bf(v.w);
        *reinterpret_cast<u16x4_t*>(d + off) = o;   // cached store: GEMMs re-read
    }
}

// -------------------------------------------------------------- layernorm ----
__global__ void layernorm_k(const float* __restrict__ x, const float* __restrict__ w,
                            const float* __restrict__ b, bf16* __restrict__ out) {
    const int row = blockIdx.x;
    const float* xr = x + (size_t)row * F_DIM;
    float v0 = xr[threadIdx.x];
    float v1 = xr[threadIdx.x + 256];
    float v2 = xr[threadIdx.x + 512];
    float s  = v0 + v1 + v2;
    float s2 = v0 * v0 + v1 * v1 + v2 * v2;
    #pragma unroll
    for (int off = 32; off; off >>= 1) {
        s  += __shfl_down(s, off);
        s2 += __shfl_down(s2, off);
    }
    __shared__ float ws_[4], ws2_[4];
    int lane = threadIdx.x & 63, wid = threadIdx.x >> 6;
    if (lane == 0) { ws_[wid] = s; ws2_[wid] = s2; }
    __syncthreads();
    float S  = ws_[0] + ws_[1] + ws_[2] + ws_[3];
    float S2 = ws2_[0] + ws2_[1] + ws2_[2] + ws2_[3];
    float mu  = S * (1.0f / F_DIM);
    float var = S2 * (1.0f / F_DIM) - mu * mu;
    float rs  = rsqrtf(var + 1e-6f);
    bf16* orow = out + (size_t)row * F_DIM;
    orow[threadIdx.x]       = __hip_bfloat16((v0 - mu) * rs * w[threadIdx.x]       + b[threadIdx.x]);
    orow[threadIdx.x + 256] = __hip_bfloat16((v1 - mu) * rs * w[threadIdx.x + 256] + b[threadIdx.x + 256]);
    orow[threadIdx.x + 512] = __hip_bfloat16((v2 - mu) * rs * w[threadIdx.x + 512] + b[threadIdx.x + 512]);
}

// ------------------------------------------------------------- bf16 GEMM -----
// (r9-proven) glds-direct staging, LDS double-buffered, 2-phase prefetch,
// ONE barrier per K-step.
template <int T, int NLOAD>
__device__ inline void stage_glds(const bf16* __restrict__ g0, int ld, int rows_rem,
                                  bf16* lds, int tid) {
    #pragma unroll
    for (int i = 0; i < NLOAD; ++i) {
        int slot = i * T + tid;
        int row = slot >> 3, s = slot & 7;
        int grow = row < rows_rem ? row : (rows_rem - 1);
        const bf16* src = g0 + (size_t)grow * ld + ((s ^ (row & 7)) * 8);
        bf16* dst = lds + (size_t)(i * T + (tid & ~63)) * 8;
        __builtin_amdgcn_global_load_lds((gptr_t)src, (lptr_t)dst, 16, 0, 0);
    }
}

template <int EPI, int BM, int BN, int WM, int WN>
__global__ __launch_bounds__((BM / (WM * 16)) * (BN / (WN * 16)) * 64)
void gemm_k(const bf16* __restrict__ A, const bf16* __restrict__ B,
            int M, int Nc, int K, int lda, int ldb,
            const float* __restrict__ p0, const float* __restrict__ p1,
            float* __restrict__ outF, float* __restrict__ outDup,
            bf16* __restrict__ outB0, bf16* __restrict__ outB1, bf16* __restrict__ outB2) {
    constexpr int NWM = BM / (WM * 16);
    constexpr int NWN = BN / (WN * 16);
    constexpr int T   = NWM * NWN * 64;
    constexpr int ALOADS = BM * 8 / T;
    constexpr int BLOADS = BN * 8 / T;

    __shared__ __align__(16) bf16 As[2][BM * 64];
    __shared__ __align__(16) bf16 Bs[2][BN * 64];

    int tx, ty;
    xcd_remap(tx, ty);
    const int tid  = threadIdx.x;
    const int lane = tid & 63, wid = tid >> 6;
    const int wr = wid / NWN, wc = wid % NWN;
    const int g4 = lane >> 4, l16 = lane & 15;
    const int bm = tx * BM, bn = ty * BN;
    const bf16* Ab = A + (size_t)bm * lda;
    const bf16* Bb = B + (size_t)bn * ldb;
    const int aRows = min(BM, M - bm);
    const int bRows = min(BN, Nc - bn);

    f32x4_t acc[WM][WN] = {};
    const int NK = K >> 6;

    stage_glds<T, ALOADS>(Ab, lda, aRows, As[0], tid);
    stage_glds<T, BLOADS>(Bb, ldb, bRows, Bs[0], tid);
    __syncthreads();

    for (int t = 0; t < NK; ++t) {
        const int c = t & 1;
        if (t + 1 < NK) {
            stage_glds<T, ALOADS>(Ab + (t + 1) * 64, lda, aRows, As[c ^ 1], tid);
            stage_glds<T, BLOADS>(Bb + (t + 1) * 64, ldb, bRows, Bs[c ^ 1], tid);
        }
        const short* AsS = reinterpret_cast<const short*>(As[c]);
        const short* BsS = reinterpret_cast<const short*>(Bs[c]);
        #pragma unroll
        for (int kk = 0; kk < 2; ++kk) {
            short8_t af[WM], bfr[WN];
            #pragma unroll
            for (int mi = 0; mi < WM; ++mi) {
                int ar = wr * WM * 16 + mi * 16 + l16;
                int j = (kk * 4 + g4) ^ (ar & 7);
                af[mi] = *reinterpret_cast<const short8_t*>(AsS + ar * 64 + j * 8);
            }
            #pragma unroll
            for (int ni = 0; ni < WN; ++ni) {
                int br = wc * WN * 16 + ni * 16 + l16;
                int j = (kk * 4 + g4) ^ (br & 7);
                bfr[ni] = *reinterpret_cast<const short8_t*>(BsS + br * 64 + j * 8);
            }
            #pragma unroll
            for (int mi = 0; mi < WM; ++mi)
                #pragma unroll
                for (int ni = 0; ni < WN; ++ni)
                    acc[mi][ni] = __builtin_amdgcn_mfma_f32_16x16x32_bf16(
                        af[mi], bfr[ni], acc[mi][ni], 0, 0, 0);
        }
        __syncthreads();
    }

    #pragma unroll
    for (int mi = 0; mi < WM; ++mi) {
        #pragma unroll
        for (int r = 0; r < 4; ++r) {
            const int row = bm + wr * WM * 16 + mi * 16 + g4 * 4 + r;
            if (row >= M) continue;
            #pragma unroll
            for (int ni = 0; ni < WN; ++ni) {
                const int col = bn + wc * WN * 16 + ni * 16 + l16;
                float v = acc[mi][ni][r];
                if (EPI == 0) {
                    if (col < F_DIM) {
                        int h = col >> 6, d = col & 63;
                        float q = (v + p0[col]) * QK_SCALE;
                        outB0[((size_t)h * NT + row) * 64 + d] = __hip_bfloat16(q);
                    } else if (col < 2 * F_DIM) {
                        int g = col - F_DIM;
                        int h = g >> 6, d = g & 63;
                        outB1[((size_t)h * NT + row) * 64 + d] = __hip_bfloat16(v);
                    } else {
                        int g = col - 2 * F_DIM;
                        int h = g >> 6, d = g & 63;
                        float vv = v + p1[g];
                        outB2[((size_t)h * 64 + d) * NTP + row] = __hip_bfloat16(vv);
                    }
                } else if (EPI == 3) {
                    size_t oi = (size_t)row * Nc + col;
                    v += p0[col];
                    float nv = outF[oi] + p1[col] * v;
                    outF[oi] = nv;
                    if (outDup) outDup[oi] = nv;
                } else if (EPI == 4) {
                    v += p0[col];
                    float g = 0.5f * v * (1.0f + erff(v * 0.70710678118654752f));
                    outB0[(size_t)row * MLPD + col] = __hip_bfloat16(g);
                }
            }
        }
    }
}

// ------------------------------------------------------- fused attention ----
// r9 structure (QB=64, 4 waves, K/V LDS dbuf, 2-phase prefetch, one barrier
// per tile).  No setprio (barrier-lockstep waves).
__global__ __launch_bounds__(256)
void flash_k(const bf16* __restrict__ q_bf, const bf16* __restrict__ k_bf,
             const bf16* __restrict__ v_t, const unsigned short* __restrict__ rp16,
             const float* __restrict__ tableT, bf16* __restrict__ o_bf) {
    __shared__ __align__(16) bf16 Qs[QB * 64];
    __shared__ __align__(16) bf16 Ks[2][KB * 64];
    __shared__ __align__(16) bf16 Vs[2][64 * KB];
    __shared__ __align__(16) bf16 Ps[4][16 * KB];

    int qx, h;
    xcd_remap(qx, h);
    const int tid = threadIdx.x, lane = tid & 63, w = tid >> 6;
    const int qb = qx * QB;
    const bf16* qh = q_bf + (size_t)h * NT * 64;
    const bf16* kh = k_bf + (size_t)h * NT * 64;
    const bf16* vh = v_t  + (size_t)h * 64 * NTP;
    const float* tbl = tableT + (size_t)h * R_REL;
    const int q_local = lane & 15;
    const int g4 = lane >> 4;

    auto stageKV = [&](int buf, int m0) {
        const int kRows = min(KB, NT - m0);
        #pragma unroll
        for (int i = 0; i < 4; ++i) {
            int slot = i * 256 + tid;
            int row = slot >> 3, s = slot & 7;
            int grow = min(row, kRows - 1);
            const bf16* src = kh + (size_t)(m0 + grow) * 64 + (s ^ (row & 7)) * 8;
            bf16* dst = Ks[buf] + (size_t)(i * 256 + (tid & ~63)) * 8;
            __builtin_amdgcn_global_load_lds((gptr_t)src, (lptr_t)dst, 16, 0, 0);
        }
        #pragma unroll
        for (int i = 0; i < 4; ++i) {
            int slot = i * 256 + tid;
            int d = slot >> 4, s = slot & 15;
            int msl = min(m0 / 8 + (s ^ (d & 15)), NTP / 8 - 1);
            const bf16* src = vh + (size_t)d * NTP + msl * 8;
            bf16* dst = Vs[buf] + (size_t)(i * 256 + (tid & ~63)) * 8;
            __builtin_amdgcn_global_load_lds((gptr_t)src, (lptr_t)dst, 16, 0, 0);
        }
    };

    // ---- stage Q + first K/V tile ----
    {
        const int qRows = min(QB, NT - qb);
        #pragma unroll
        for (int i = 0; i < 2; ++i) {
            int slot = i * 256 + tid;
            int row = slot >> 3, s = slot & 7;
            int grow = min(row, qRows - 1);
            const bf16* src = qh + (size_t)(qb + grow) * 64 + (s ^ (row & 7)) * 8;
            bf16* dst = Qs + (size_t)(i * 256 + (tid & ~63)) * 8;
            __builtin_amdgcn_global_load_lds((gptr_t)src, (lptr_t)dst, 16, 0, 0);
        }
    }
    stageKV(0, 0);
    __syncthreads();

    short8_t qf[2];
    {
        const short* QsS = (const short*)Qs;
        #pragma unroll
        for (int kk = 0; kk < 2; ++kk) {
            int row = w * 16 + q_local;
            int slot = (kk * 4 + g4) ^ (row & 7);
            qf[kk] = *(const short8_t*)(QsS + row * 64 + slot * 8);
        }
    }

    float m_run[4], l_run[4];
    f32x4_t acc[4] = {};
    #pragma unroll
    for (int r = 0; r < 4; ++r) { m_run[r] = -1e30f; l_run[r] = 0.0f; }

    const int NTILES = (NT + KB - 1) / KB;   // 9
    for (int t = 0; t < NTILES; ++t) {
        const int m0 = t * KB;
        const int c = t & 1;
        if (t + 1 < NTILES) stageKV(c ^ 1, (t + 1) * KB);  // prefetch next tile

        f32x4_t sfr[8];
        {
            const short* KsS = (const short*)Ks[c];
            #pragma unroll
            for (int f = 0; f < 8; ++f) {
                f32x4_t cacc = {};
                #pragma unroll
                for (int kk = 0; kk < 2; ++kk) {
                    int mrow = f * 16 + q_local;
                    int slot = (kk * 4 + g4) ^ (mrow & 7);
                    short8_t bv = *(const short8_t*)(KsS + mrow * 64 + slot * 8);
                    cacc = __builtin_amdgcn_mfma_f32_16x16x32_bf16(qf[kk], bv, cacc, 0, 0, 0);
                }
                sfr[f] = cacc;
            }
        }

        const int qrow_base = qb + w * 16 + g4 * 4;
        #pragma unroll
        for (int f = 0; f < 8; ++f) {
            int mm = m0 + f * 16 + q_local;
            if (mm < NT) {
                #pragma unroll
                for (int r = 0; r < 4; ++r) {
                    int qc = min(qrow_base + r, NT - 1);
                    int idx = rp16[(size_t)qc * NT + mm];
                    sfr[f][r] += tbl[idx];
                }
            } else {
                #pragma unroll
                for (int r = 0; r < 4; ++r) sfr[f][r] = -1e30f;
            }
        }

        float pmax[4];
        #pragma unroll
        for (int r = 0; r < 4; ++r) {
            float mx = sfr[0][r];
            #pragma unroll
            for (int f = 1; f < 8; ++f) mx = fmaxf(mx, sfr[f][r]);
            pmax[r] = mx;
        }
        #pragma unroll
        for (int off = 1; off < 16; off <<= 1)
            #pragma unroll
            for (int r = 0; r < 4; ++r) pmax[r] = fmaxf(pmax[r], __shfl_xor(pmax[r], off));

        float fac[4];
        #pragma unroll
        for (int r = 0; r < 4; ++r) {
            float mnew = fmaxf(m_run[r], pmax[r]);
            fac[r] = __expf(m_run[r] - mnew);
            m_run[r] = mnew;
        }

        float rsum[4] = {0.f, 0.f, 0.f, 0.f};
        short* PsW = (short*)Ps[w];
        #pragma unroll
        for (int f = 0; f < 8; ++f) {
            int mloc = f * 16 + q_local;
            #pragma unroll
            for (int r = 0; r < 4; ++r) {
                int ql = g4 * 4 + r;
                float p = __expf(sfr[f][r] - m_run[r]);
                rsum[r] += p;
                PsW[ql * 128 + (((mloc >> 3) ^ ql) * 8) + (mloc & 7)] = (short)f2bf(p);
            }
        }
        #pragma unroll
        for (int off = 1; off < 16; off <<= 1)
            #pragma unroll
            for (int r = 0; r < 4; ++r) rsum[r] += __shfl_xor(rsum[r], off);
        #pragma unroll
        for (int r = 0; r < 4; ++r) l_run[r] = l_run[r] * fac[r] + rsum[r];
        #pragma unroll
        for (int df = 0; df < 4; ++df)
            #pragma unroll
            for (int r = 0; r < 4; ++r) acc[df][r] *= fac[r];

        {
            const short* PsR = (const short*)Ps[w];
            const short* VsS = (const short*)Vs[c];
            #pragma unroll
            for (int kk = 0; kk < 4; ++kk) {
                int j = kk * 4 + g4;
                short8_t pa = *(const short8_t*)(PsR + q_local * 128 + (j ^ q_local) * 8);
                #pragma unroll
                for (int df = 0; df < 4; ++df) {
                    int drow = df * 16 + q_local;
                    short8_t vb = *(const short8_t*)(VsS + drow * 128 + (j ^ (drow & 15)) * 8);
                    acc[df] = __builtin_amdgcn_mfma_f32_16x16x32_bf16(pa, vb, acc[df], 0, 0, 0);
                }
            }
        }
        __syncthreads();   // one barrier/tile: drains prefetch, frees buf c
    }

    #pragma unroll
    for (int df = 0; df < 4; ++df) {
        #pragma unroll
        for (int r = 0; r < 4; ++r) {
            int qq = qb + w * 16 + g4 * 4 + r;
            if (qq < NT) {
                float o = acc[df][r] / l_run[r];
                o_bf[(size_t)qq * F_DIM + h * 64 + df * 16 + q_local] = __hip_bfloat16(o);
            }
        }
    }
}

// ------------------------------------------------------------------- host ----
extern "C" void kernel_launch(void* const* d_in, const int* in_sizes, int n_in,
                              void* d_out, int out_size, void* d_ws, size_t ws_size,
                              hipStream_t stream) {
    const float* patch      = (const float*)d_in[0];
    const float* cls        = (const float*)d_in[1];
    const float* ln1_w      = (const float*)d_in[2];
    const float* ln1_b      = (const float*)d_in[3];
    const float* qkv_w      = (const float*)d_in[4];
    const float* q_bias     = (const float*)d_in[5];
    const float* v_bias     = (const float*)d_in[6];
    const float* proj_w     = (const float*)d_in[7];
    const float* proj_b     = (const float*)d_in[8];
    const float* scale_attn = (const float*)d_in[9];
    const float* ln2_w      = (const float*)d_in[10];
    const float* ln2_b      = (const float*)d_in[11];
    const float* fc1_w      = (const float*)d_in[12];
    const float* fc1_b      = (const float*)d_in[13];
    const float* fc2_w      = (const float*)d_in[14];
    const float* fc2_b      = (const float*)d_in[15];
    const float* scale_mlp  = (const float*)d_in[16];
    const float* table      = (const float*)d_in[17];
    const int*   rp_idx     = (const int*)d_in[18];
    float* out = (float*)d_out;

    char* ws = (char*)d_ws;
    size_t off = 0;
    auto alloc = [&](size_t bytes) { char* p = ws + off; off += (bytes + 255) & ~255ULL; return p; };

    float* x      = (float*)alloc((size_t)NT * F_DIM * 4);
    bf16*  h_bf   = (bf16*) alloc((size_t)NT * F_DIM * 2);
    bf16*  q_bf   = (bf16*) alloc((size_t)H_HEADS * NT * 64 * 2);
    bf16*  k_bf   = (bf16*) alloc((size_t)H_HEADS * NT * 64 * 2);
    bf16*  v_t    = (bf16*) alloc((size_t)H_HEADS * 64 * NTP * 2);
    bf16*  o_bf   = (bf16*) alloc((size_t)NT * F_DIM * 2);
    bf16*  m1_bf  = (bf16*) alloc((size_t)NT * MLPD * 2);
    unsigned short* rp16 = (unsigned short*)alloc((size_t)NT * NT * 2);
    float* tableT = (float*)alloc((size_t)L_LAYERS * H_HEADS * R_REL * 4);
    bf16*  wq_all = (bf16*) alloc((size_t)L_LAYERS * CQKV * 2);
    bf16*  wp_all = (bf16*) alloc((size_t)L_LAYERS * CPROJ * 2);
    bf16*  w1_all = (bf16*) alloc((size_t)L_LAYERS * CFC1 * 2);
    bf16*  w2_all = (bf16*) alloc((size_t)L_LAYERS * CFC2 * 2);

    setup_k<<<2048, 256, 0, stream>>>(patch, cls, rp_idx, table, x, v_t, rp16, tableT);
    conv_all_k<<<2048, 256, 0, stream>>>(qkv_w, proj_w, fc1_w, fc2_w,
                                         wq_all, wp_all, w1_all, w2_all);

    int stage = 0;
    for (int l = 0; l < L_LAYERS; ++l) {
        layernorm_k<<<NT, 256, 0, stream>>>(x, ln1_w + l * F_DIM, ln1_b + l * F_DIM, h_bf);

        gemm_k<0, 64, 128, 2, 2><<<dim3(17, 18), 512, 0, stream>>>(
            h_bf, wq_all + (size_t)l * CQKV, NT, THREE_F, F_DIM, F_DIM, F_DIM,
            q_bias + (size_t)l * F_DIM, v_bias + (size_t)l * F_DIM,
            nullptr, nullptr, q_bf, k_bf, v_t);

        flash_k<<<dim3((NT + QB - 1) / QB, H_HEADS), 256, 0, stream>>>(
            q_bf, k_bf, v_t, rp16,
            tableT + (size_t)l * H_HEADS * R_REL, o_bf);

        gemm_k<3, 32, 64, 1, 2><<<dim3(33, 12), 256, 0, stream>>>(
            o_bf, wp_all + (size_t)l * CPROJ, NT, F_DIM, F_DIM, F_DIM, F_DIM,
            proj_b + (size_t)l * F_DIM, scale_attn + (size_t)l * F_DIM,
            x, nullptr, nullptr, nullptr, nullptr);

        layernorm_k<<<NT, 256, 0, stream>>>(x, ln2_w + l * F_DIM, ln2_b + l * F_DIM, h_bf);

        gemm_k<4, 64, 128, 2, 2><<<dim3(17, 24), 512, 0, stream>>>(
            h_bf, w1_all + (size_t)l * CFC1, NT, MLPD, F_DIM, F_DIM, F_DIM,
            fc1_b + (size_t)l * MLPD, nullptr,
            nullptr, nullptr, m1_bf, nullptr, nullptr);

        const bool isStage = (l == 2 || l == 5 || l == 8 || l == 11);
        float* outDup = isStage ? (out + (size_t)stage * NT * F_DIM) : nullptr;
        gemm_k<3, 32, 64, 1, 2><<<dim3(33, 12), 256, 0, stream>>>(
            m1_bf, w2_all + (size_t)l * CFC2, NT, F_DIM, MLPD, MLPD, MLPD,
            fc2_b + (size_t)l * F_DIM, scale_mlp + (size_t)l * F_DIM,
            x, outDup, nullptr, nullptr, nullptr);
        if (isStage) ++stage;
    }
}